// Round 1
// baseline (1533.253 us; speedup 1.0000x reference)
//
#include <hip/hip_runtime.h>
#include <hip/hip_bf16.h>

// Problem constants (B=8, C=512, H=W=64, HEADS=8, HEAD_DIM=64)
#define BATCH 8
#define CDIM 512
#define NPIX 4096            // 64*64
#define NHEAD 8
#define HDIM 64
#define ATT_SCALE 0.125f     // HEAD_DIM^-0.5
#define L2EPS 1e-12f

// ---------------------------------------------------------------------------
// 1) depthwise 3x3, padding 1.  x:[B,C,64,64] -> y:[B,C,64,64]
// ---------------------------------------------------------------------------
__global__ __launch_bounds__(256) void dwconv3x3(const float* __restrict__ x,
                                                 const float* __restrict__ w,
                                                 float* __restrict__ y) {
    int idx = blockIdx.x * 256 + threadIdx.x;        // over B*C*N = 16.78M
    int n  = idx & (NPIX - 1);
    int bc = idx >> 12;                              // b*512 + c
    int c  = bc & (CDIM - 1);
    int px = n & 63, py = n >> 6;
    const float* wp = w + c * 9;
    const float* xp = x + (size_t)bc * NPIX;
    float acc = 0.f;
#pragma unroll
    for (int ky = 0; ky < 3; ++ky) {
        int yy = py + ky - 1;
        if (yy < 0 || yy > 63) continue;
#pragma unroll
        for (int kx = 0; kx < 3; ++kx) {
            int xx = px + kx - 1;
            if (xx < 0 || xx > 63) continue;
            acc += wp[ky * 3 + kx] * xp[yy * 64 + xx];
        }
    }
    y[idx] = acc;
}

// ---------------------------------------------------------------------------
// 2) conv1x1 as fp32 GEMM:  Y[b][o][n] = sum_c W[o][c] * X[b][c][n]
//    grid (N/64, O/64, B), block 256 (16x16), 4x4 micro-tile, K-chunk 16.
// ---------------------------------------------------------------------------
__global__ __launch_bounds__(256) void conv1x1_gemm(const float* __restrict__ Wm,
                                                    const float* __restrict__ X,
                                                    float* __restrict__ Y) {
    __shared__ float As[64][17];   // [o_local][k]  (+1 pad)
    __shared__ float Bs[16][68];   // [k][n_local]  (+4 pad, float4-aligned rows)
    const int tid = threadIdx.x;
    const int tx = tid & 15, ty = tid >> 4;
    const int n0 = blockIdx.x * 64;
    const int o0 = blockIdx.y * 64;
    const int b  = blockIdx.z;
    const float* Xb = X + (size_t)b * (CDIM * NPIX);

    const int ar = tid >> 2;           // 0..63 A row
    const int ak = (tid & 3) * 4;      // A k offset (float4)
    const int bk = tid >> 4;           // 0..15 B k row
    const int bn = (tid & 15) * 4;     // B n offset (float4)

    float acc[4][4] = {};
    for (int k0 = 0; k0 < CDIM; k0 += 16) {
        const float4 av = *(const float4*)(Wm + (size_t)(o0 + ar) * CDIM + k0 + ak);
        const float4 bv = *(const float4*)(Xb + (size_t)(k0 + bk) * NPIX + n0 + bn);
        As[ar][ak + 0] = av.x; As[ar][ak + 1] = av.y;
        As[ar][ak + 2] = av.z; As[ar][ak + 3] = av.w;
        *(float4*)&Bs[bk][bn] = bv;
        __syncthreads();
#pragma unroll
        for (int kk = 0; kk < 16; ++kk) {
            float a[4], bb[4];
#pragma unroll
            for (int i = 0; i < 4; ++i) a[i] = As[i * 16 + ty][kk];
#pragma unroll
            for (int j = 0; j < 4; ++j) bb[j] = Bs[kk][j * 16 + tx];
#pragma unroll
            for (int i = 0; i < 4; ++i)
#pragma unroll
                for (int j = 0; j < 4; ++j) acc[i][j] += a[i] * bb[j];
        }
        __syncthreads();
    }
#pragma unroll
    for (int i = 0; i < 4; ++i) {
        const size_t orow = (size_t)b * (CDIM * NPIX) + (size_t)(o0 + i * 16 + ty) * NPIX;
#pragma unroll
        for (int j = 0; j < 4; ++j) Y[orow + n0 + j * 16 + tx] = acc[i][j];
    }
}

// ---------------------------------------------------------------------------
// 3) reciprocal L2 norm per row of [4096 rows][4096 cols]
// ---------------------------------------------------------------------------
__global__ __launch_bounds__(256) void rownorm256(const float* __restrict__ X,
                                                  float* __restrict__ rn) {
    const int row = blockIdx.x;
    const float4* xp = (const float4*)(X + (size_t)row * NPIX);
    float s = 0.f;
    for (int i = threadIdx.x; i < NPIX / 4; i += 256) {
        float4 v = xp[i];
        s += v.x * v.x + v.y * v.y + v.z * v.z + v.w * v.w;
    }
#pragma unroll
    for (int off = 32; off; off >>= 1) s += __shfl_down(s, off);
    __shared__ float ss[4];
    if ((threadIdx.x & 63) == 0) ss[threadIdx.x >> 6] = s;
    __syncthreads();
    if (threadIdx.x == 0) {
        float t = ss[0] + ss[1] + ss[2] + ss[3];
        rn[row] = 1.0f / fmaxf(sqrtf(t), L2EPS);
    }
}

// ---------------------------------------------------------------------------
// 4) partial QK^T: Spart[bh][chunk][d][e] = sum_{n in chunk(256)} q[d,n]k[e,n]
//    grid (16 chunks, 64 bh), block 256.
// ---------------------------------------------------------------------------
__global__ __launch_bounds__(256) void qk_partial(const float* __restrict__ Q,
                                                  const float* __restrict__ K,
                                                  float* __restrict__ Spart) {
    __shared__ float Qs[64][68];
    __shared__ float Ks[64][68];
    const int tid = threadIdx.x;
    const int tx = tid & 15, ty = tid >> 4;
    const int n0 = blockIdx.x * 256;
    const int bh = blockIdx.y;
    const float* Qb = Q + (size_t)bh * HDIM * NPIX;
    const float* Kb = K + (size_t)bh * HDIM * NPIX;
    float acc[4][4] = {};
    for (int sub = 0; sub < 4; ++sub) {
        const int nn0 = n0 + sub * 64;
#pragma unroll
        for (int r = 0; r < 4; ++r) {
            int id = tid + r * 256;       // 0..1023 float4 slots
            int row = id >> 4;
            int col = (id & 15) << 2;
            *(float4*)&Qs[row][col] = *(const float4*)(Qb + (size_t)row * NPIX + nn0 + col);
            *(float4*)&Ks[row][col] = *(const float4*)(Kb + (size_t)row * NPIX + nn0 + col);
        }
        __syncthreads();
#pragma unroll
        for (int kk = 0; kk < 64; ++kk) {
            float a[4], bb[4];
#pragma unroll
            for (int i = 0; i < 4; ++i) a[i] = Qs[i * 16 + ty][kk];
#pragma unroll
            for (int j = 0; j < 4; ++j) bb[j] = Ks[j * 16 + tx][kk];
#pragma unroll
            for (int i = 0; i < 4; ++i)
#pragma unroll
                for (int j = 0; j < 4; ++j) acc[i][j] += a[i] * bb[j];
        }
        __syncthreads();
    }
    float* sp = Spart + ((size_t)bh * 16 + blockIdx.x) * 4096;
#pragma unroll
    for (int i = 0; i < 4; ++i)
#pragma unroll
        for (int j = 0; j < 4; ++j)
            sp[(i * 16 + ty) * 64 + j * 16 + tx] = acc[i][j];
}

// ---------------------------------------------------------------------------
// 5) reduce partials, apply norms+scale, softmax over e, fold rv into P
//    P[bh][d][e] = softmax_e( Spart_sum * rq[d]*rk[e]*scale ) * rv[e]
// ---------------------------------------------------------------------------
__global__ __launch_bounds__(64) void softmax_p(const float* __restrict__ Spart,
                                                const float* __restrict__ rq,
                                                const float* __restrict__ rk,
                                                const float* __restrict__ rv,
                                                float* __restrict__ P) {
    const int bh = blockIdx.x;
    const int d = threadIdx.x;    // 0..63
    __shared__ float rks[64], rvs[64];
    rks[d] = rk[bh * 64 + d];
    rvs[d] = rv[bh * 64 + d];
    __syncthreads();
    const float rqd = rq[bh * 64 + d] * ATT_SCALE;
    const float* sp = Spart + (size_t)bh * (16 * 4096) + d * 64;
    float srow[64];
#pragma unroll
    for (int e = 0; e < 64; ++e) {
        float s = 0.f;
#pragma unroll
        for (int c = 0; c < 16; ++c) s += sp[c * 4096 + e];
        srow[e] = s * rqd * rks[e];
    }
    float m = -1e30f;
#pragma unroll
    for (int e = 0; e < 64; ++e) m = fmaxf(m, srow[e]);
    float sum = 0.f;
#pragma unroll
    for (int e = 0; e < 64; ++e) { float p = expf(srow[e] - m); srow[e] = p; sum += p; }
    const float inv = 1.f / sum;
    float* pp = P + (size_t)bh * 4096 + d * 64;
#pragma unroll
    for (int e = 0; e < 64; ++e) pp[e] = srow[e] * inv * rvs[e];
}

// ---------------------------------------------------------------------------
// 6) O[bh][d][n] = sum_e P[bh][d][e] * V[bh][e][n]
//    grid (16 n-chunks, 64 bh), block 256; one n-column per thread, acc[64].
// ---------------------------------------------------------------------------
__global__ __launch_bounds__(256) void pv_kernel(const float* __restrict__ P,
                                                 const float* __restrict__ V,
                                                 float* __restrict__ O) {
    __shared__ float Ps[64][64];
    const int tid = threadIdx.x;
    const int bh = blockIdx.y;
    const int n = blockIdx.x * 256 + tid;
    const float* Pb = P + (size_t)bh * 4096;
#pragma unroll
    for (int r = 0; r < 4; ++r) {
        int id = tid + r * 256;
        int row = id >> 4;
        int col = (id & 15) << 2;
        *(float4*)&Ps[row][col] = *(const float4*)(Pb + row * 64 + col);
    }
    __syncthreads();
    float acc[64];
#pragma unroll
    for (int d = 0; d < 64; ++d) acc[d] = 0.f;
    const float* Vb = V + (size_t)bh * HDIM * NPIX + n;
#pragma unroll 1
    for (int e = 0; e < 64; ++e) {
        float vv = Vb[(size_t)e * NPIX];
#pragma unroll
        for (int d = 0; d < 64; ++d) acc[d] += Ps[d][e] * vv;
    }
    float* Ob = O + (size_t)bh * HDIM * NPIX + n;
#pragma unroll 1
    for (int d = 0; d < 64; ++d) Ob[(size_t)d * NPIX] = acc[d];
}

// ---------------------------------------------------------------------------
extern "C" void kernel_launch(void* const* d_in, const int* in_sizes, int n_in,
                              void* d_out, int out_size, void* d_ws, size_t ws_size,
                              hipStream_t stream) {
    (void)in_sizes; (void)n_in; (void)out_size; (void)ws_size;
    const float* x      = (const float*)d_in[0];
    const float* dw_w   = (const float*)d_in[1];
    const float* q_w    = (const float*)d_in[2];
    const float* k_w    = (const float*)d_in[3];
    const float* v_w    = (const float*)d_in[4];
    const float* proj_w = (const float*)d_in[5];
    float* out = (float*)d_out;

    const size_t SZ = (size_t)BATCH * CDIM * NPIX;   // 16,777,216 floats
    float* ws = (float*)d_ws;
    float* xd = ws;               // dwconv output; region reused for Spart/P later
    float* q  = ws + SZ;          // reused for attention output (out2) later
    float* k  = ws + 2 * SZ;
    float* rq = ws + 3 * SZ;      // 4096 each
    float* rk = rq + 4096;
    float* rv = rk + 4096;
    float* v  = out;              // v lives in d_out; overwritten by proj at the end
    float* Spart = xd;                          // 64*16*4096 floats
    float* P  = xd + (size_t)64 * 16 * 4096;    // 64*4096 floats
    float* out2 = q;

    // 1) depthwise conv
    dwconv3x3<<<dim3((BATCH * CDIM * NPIX) / 256), 256, 0, stream>>>(x, dw_w, xd);

    // 2) q,k,v conv1x1 GEMMs
    dim3 gg(NPIX / 64, CDIM / 64, BATCH);
    conv1x1_gemm<<<gg, 256, 0, stream>>>(q_w, xd, q);
    conv1x1_gemm<<<gg, 256, 0, stream>>>(k_w, xd, k);
    conv1x1_gemm<<<gg, 256, 0, stream>>>(v_w, xd, v);

    // 3) reciprocal L2 norms of each (b,h,d) row
    rownorm256<<<BATCH * CDIM, 256, 0, stream>>>(q, rq);
    rownorm256<<<BATCH * CDIM, 256, 0, stream>>>(k, rk);
    rownorm256<<<BATCH * CDIM, 256, 0, stream>>>(v, rv);

    // 4) chunked QK^T partials (xd region is dead now -> Spart)
    qk_partial<<<dim3(16, BATCH * NHEAD), 256, 0, stream>>>(q, k, Spart);

    // 5) softmax (+ fold in rq,rk,scale,rv)
    softmax_p<<<BATCH * NHEAD, 64, 0, stream>>>(Spart, rq, rk, rv, P);

    // 6) attention output (q region is dead now -> out2)
    pv_kernel<<<dim3(16, BATCH * NHEAD), 256, 0, stream>>>(P, v, out2);

    // 7) projection conv1x1 (reads out2, overwrites d_out which held v)
    conv1x1_gemm<<<gg, 256, 0, stream>>>(proj_w, out2, out);
}

// Round 2
// 588.065 us; speedup vs baseline: 2.6073x; 2.6073x over previous
//
#include <hip/hip_runtime.h>
#include <hip/hip_bf16.h>

// Problem constants (B=8, C=512, H=W=64, HEADS=8, HEAD_DIM=64)
#define BATCH 8
#define CDIM 512
#define NPIX 4096            // 64*64
#define NHEAD 8
#define HDIM 64
#define ATT_SCALE 0.125f     // HEAD_DIM^-0.5
#define L2EPS 1e-12f

typedef __attribute__((ext_vector_type(8))) short short8;   // 8 bf16 (4 VGPRs)
typedef __attribute__((ext_vector_type(4))) float f32x4;    // MFMA C/D

typedef const __attribute__((address_space(1))) void* gas_ptr;
typedef __attribute__((address_space(3))) void* las_ptr;

__device__ __forceinline__ void ld_lds16(const void* g, void* l) {
    // async global->LDS, 16B/lane. LDS dest = wave-uniform base + lane*16.
    __builtin_amdgcn_global_load_lds((gas_ptr)g, (las_ptr)l, 16, 0, 0);
}

// ---------------------------------------------------------------------------
// 1) depthwise 3x3, padding 1.  x:[B,C,64,64] -> y:[B,C,64,64]  (fp32)
// ---------------------------------------------------------------------------
__global__ __launch_bounds__(256) void dwconv3x3(const float* __restrict__ x,
                                                 const float* __restrict__ w,
                                                 float* __restrict__ y) {
    int idx = blockIdx.x * 256 + threadIdx.x;        // over B*C*N = 16.78M
    int n  = idx & (NPIX - 1);
    int bc = idx >> 12;                              // b*512 + c
    int c  = bc & (CDIM - 1);
    int px = n & 63, py = n >> 6;
    const float* wp = w + c * 9;
    const float* xp = x + (size_t)bc * NPIX;
    float acc = 0.f;
#pragma unroll
    for (int ky = 0; ky < 3; ++ky) {
        int yy = py + ky - 1;
        if (yy < 0 || yy > 63) continue;
#pragma unroll
        for (int kx = 0; kx < 3; ++kx) {
            int xx = px + kx - 1;
            if (xx < 0 || xx > 63) continue;
            acc += wp[ky * 3 + kx] * xp[yy * 64 + xx];
        }
    }
    y[idx] = acc;
}

// ---------------------------------------------------------------------------
// 2) transpose + cast: X[b][C=512][N=4096] fp32 -> XT[b][N][C] bf16
//    64x64 tiles. grid (N/64, C/64, B), block 256.
// ---------------------------------------------------------------------------
__global__ __launch_bounds__(256) void transpose_cast(const float* __restrict__ X,
                                                      __hip_bfloat16* __restrict__ XT) {
    __shared__ float tile[64][65];
    const int tid = threadIdx.x;
    const int n0 = blockIdx.x * 64;
    const int c0 = blockIdx.y * 64;
    const int b  = blockIdx.z;
    const float* Xb = X + (size_t)b * (CDIM * NPIX);
    const int lo = tid & 63, hi = tid >> 6;   // hi in 0..3
#pragma unroll
    for (int i = 0; i < 16; ++i) {
        int cl = i * 4 + hi;
        tile[cl][lo] = Xb[(size_t)(c0 + cl) * NPIX + n0 + lo];
    }
    __syncthreads();
    __hip_bfloat16* XTb = XT + (size_t)b * (NPIX * CDIM);
#pragma unroll
    for (int i = 0; i < 16; ++i) {
        int nl = i * 4 + hi;
        XTb[(size_t)(n0 + nl) * CDIM + c0 + lo] = __float2bfloat16(tile[lo][nl]);
    }
}

// ---------------------------------------------------------------------------
// 3) cast the four 512x512 fp32 weight matrices to bf16
// ---------------------------------------------------------------------------
__global__ __launch_bounds__(256) void cast_weights(const float* __restrict__ s0,
                                                    const float* __restrict__ s1,
                                                    const float* __restrict__ s2,
                                                    const float* __restrict__ s3,
                                                    __hip_bfloat16* __restrict__ d0,
                                                    __hip_bfloat16* __restrict__ d1,
                                                    __hip_bfloat16* __restrict__ d2,
                                                    __hip_bfloat16* __restrict__ d3) {
    int i = blockIdx.x * 256 + threadIdx.x;   // 0..262143
    const float* s = (blockIdx.y == 0) ? s0 : (blockIdx.y == 1) ? s1 : (blockIdx.y == 2) ? s2 : s3;
    __hip_bfloat16* d = (blockIdx.y == 0) ? d0 : (blockIdx.y == 1) ? d1 : (blockIdx.y == 2) ? d2 : d3;
    d[i] = __float2bfloat16(s[i]);
}

// ---------------------------------------------------------------------------
// 4) bf16 MFMA GEMM (m97 structure): Y[b][o][n] = sum_c W[o][c] * X[b][c][n]
//    W: [512][512] bf16 row-major (k-contig). XT: [b][4096][512] bf16 (k-contig).
//    128x128 tile, 4 waves, each wave 64x64 via 4x4 mfma_f32_16x16x32_bf16.
//    grid (N/128=32, M/128=4, B), block 256.
// ---------------------------------------------------------------------------
__global__ __launch_bounds__(256) void gemm_bf16(const __hip_bfloat16* __restrict__ W,
                                                 const __hip_bfloat16* __restrict__ XT,
                                                 float* __restrict__ Y) {
    __shared__ __align__(16) short As[128 * 32];   // [m][k]
    __shared__ __align__(16) short Bs[128 * 32];   // [n][k]
    const int tid  = threadIdx.x;
    const int wave = tid >> 6;
    const int lane = tid & 63;
    const int n0 = blockIdx.x * 128;
    const int o0 = blockIdx.y * 128;
    const int b  = blockIdx.z;

    const short* Wg = (const short*)W + (size_t)o0 * CDIM;
    const short* Xg = (const short*)XT + ((size_t)b * NPIX + n0) * CDIM;

    const int am = (wave >> 1) * 64;     // wave's m-origin in tile
    const int bn = (wave & 1) * 64;      // wave's n-origin in tile
    const int lrow = lane & 15;
    const int lk   = (lane >> 4) * 8;

    f32x4 acc[4][4] = {};

    for (int k0 = 0; k0 < CDIM; k0 += 32) {
        // stage A and B tiles: 512 16B-chunks each, 2 per thread per tile
#pragma unroll
        for (int i = 0; i < 2; ++i) {
            const int q = i * 256 + tid;          // chunk index 0..511
            const int r = q >> 2;                 // tile row 0..127
            const int c = (q & 3) * 8;            // short offset within 32-wide row
            const int ldsoff = (i * 256 + wave * 64) * 8;   // wave-uniform (shorts)
            ld_lds16(Wg + (size_t)r * CDIM + k0 + c, As + ldsoff);
            ld_lds16(Xg + (size_t)r * CDIM + k0 + c, Bs + ldsoff);
        }
        __syncthreads();   // drains vmcnt -> LDS visible

        short8 afrag[4], bfrag[4];
#pragma unroll
        for (int i = 0; i < 4; ++i)
            afrag[i] = *(const short8*)&As[(am + i * 16 + lrow) * 32 + lk];
#pragma unroll
        for (int j = 0; j < 4; ++j)
            bfrag[j] = *(const short8*)&Bs[(bn + j * 16 + lrow) * 32 + lk];
#pragma unroll
        for (int i = 0; i < 4; ++i)
#pragma unroll
            for (int j = 0; j < 4; ++j)
                acc[i][j] = __builtin_amdgcn_mfma_f32_16x16x32_bf16(afrag[i], bfrag[j],
                                                                   acc[i][j], 0, 0, 0);
        __syncthreads();   // before overwriting LDS next iter
    }

    // epilogue: C/D layout col=lane&15, row=(lane>>4)*4+reg  [m89/m91-verified]
    const int crow = (lane >> 4) * 4;
    const int ccol = lane & 15;
    float* Yb = Y + (size_t)b * (CDIM * NPIX);
#pragma unroll
    for (int i = 0; i < 4; ++i) {
#pragma unroll
        for (int j = 0; j < 4; ++j) {
#pragma unroll
            for (int r = 0; r < 4; ++r) {
                const int om = o0 + am + i * 16 + crow + r;
                const int on = n0 + bn + j * 16 + ccol;
                Yb[(size_t)om * NPIX + on] = acc[i][j][r];
            }
        }
    }
}

// ---------------------------------------------------------------------------
// 5) reciprocal L2 norm per row of [4096 rows][4096 cols]
// ---------------------------------------------------------------------------
__global__ __launch_bounds__(256) void rownorm256(const float* __restrict__ X,
                                                  float* __restrict__ rn) {
    const int row = blockIdx.x;
    const float4* xp = (const float4*)(X + (size_t)row * NPIX);
    float s = 0.f;
    for (int i = threadIdx.x; i < NPIX / 4; i += 256) {
        float4 v = xp[i];
        s += v.x * v.x + v.y * v.y + v.z * v.z + v.w * v.w;
    }
#pragma unroll
    for (int off = 32; off; off >>= 1) s += __shfl_down(s, off);
    __shared__ float ss[4];
    if ((threadIdx.x & 63) == 0) ss[threadIdx.x >> 6] = s;
    __syncthreads();
    if (threadIdx.x == 0) {
        float t = ss[0] + ss[1] + ss[2] + ss[3];
        rn[row] = 1.0f / fmaxf(sqrtf(t), L2EPS);
    }
}

// ---------------------------------------------------------------------------
// 6) partial QK^T: Spart[bh][chunk][d][e] = sum_{n in chunk(256)} q[d,n]k[e,n]
// ---------------------------------------------------------------------------
__global__ __launch_bounds__(256) void qk_partial(const float* __restrict__ Q,
                                                  const float* __restrict__ K,
                                                  float* __restrict__ Spart) {
    __shared__ float Qs[64][68];
    __shared__ float Ks[64][68];
    const int tid = threadIdx.x;
    const int tx = tid & 15, ty = tid >> 4;
    const int n0 = blockIdx.x * 256;
    const int bh = blockIdx.y;
    const float* Qb = Q + (size_t)bh * HDIM * NPIX;
    const float* Kb = K + (size_t)bh * HDIM * NPIX;
    float acc[4][4] = {};
    for (int sub = 0; sub < 4; ++sub) {
        const int nn0 = n0 + sub * 64;
#pragma unroll
        for (int r = 0; r < 4; ++r) {
            int id = tid + r * 256;       // 0..1023 float4 slots
            int row = id >> 4;
            int col = (id & 15) << 2;
            *(float4*)&Qs[row][col] = *(const float4*)(Qb + (size_t)row * NPIX + nn0 + col);
            *(float4*)&Ks[row][col] = *(const float4*)(Kb + (size_t)row * NPIX + nn0 + col);
        }
        __syncthreads();
#pragma unroll
        for (int kk = 0; kk < 64; ++kk) {
            float a[4], bb[4];
#pragma unroll
            for (int i = 0; i < 4; ++i) a[i] = Qs[i * 16 + ty][kk];
#pragma unroll
            for (int j = 0; j < 4; ++j) bb[j] = Ks[j * 16 + tx][kk];
#pragma unroll
            for (int i = 0; i < 4; ++i)
#pragma unroll
                for (int j = 0; j < 4; ++j) acc[i][j] += a[i] * bb[j];
        }
        __syncthreads();
    }
    float* sp = Spart + ((size_t)bh * 16 + blockIdx.x) * 4096;
#pragma unroll
    for (int i = 0; i < 4; ++i)
#pragma unroll
        for (int j = 0; j < 4; ++j)
            sp[(i * 16 + ty) * 64 + j * 16 + tx] = acc[i][j];
}

// ---------------------------------------------------------------------------
// 7) reduce partials, apply norms+scale, softmax over e, fold rv into P
// ---------------------------------------------------------------------------
__global__ __launch_bounds__(64) void softmax_p(const float* __restrict__ Spart,
                                                const float* __restrict__ rq,
                                                const float* __restrict__ rk,
                                                const float* __restrict__ rv,
                                                float* __restrict__ P) {
    const int bh = blockIdx.x;
    const int d = threadIdx.x;    // 0..63
    __shared__ float rks[64], rvs[64];
    rks[d] = rk[bh * 64 + d];
    rvs[d] = rv[bh * 64 + d];
    __syncthreads();
    const float rqd = rq[bh * 64 + d] * ATT_SCALE;
    const float* sp = Spart + (size_t)bh * (16 * 4096) + d * 64;
    float srow[64];
#pragma unroll
    for (int e = 0; e < 64; ++e) {
        float s = 0.f;
#pragma unroll
        for (int c = 0; c < 16; ++c) s += sp[c * 4096 + e];
        srow[e] = s * rqd * rks[e];
    }
    float m = -1e30f;
#pragma unroll
    for (int e = 0; e < 64; ++e) m = fmaxf(m, srow[e]);
    float sum = 0.f;
#pragma unroll
    for (int e = 0; e < 64; ++e) { float p = expf(srow[e] - m); srow[e] = p; sum += p; }
    const float inv = 1.f / sum;
    float* pp = P + (size_t)bh * 4096 + d * 64;
#pragma unroll
    for (int e = 0; e < 64; ++e) pp[e] = srow[e] * inv * rvs[e];
}

// ---------------------------------------------------------------------------
// 8) O[bh][d][n] = sum_e P[bh][d][e] * V[bh][e][n]
// ---------------------------------------------------------------------------
__global__ __launch_bounds__(256) void pv_kernel(const float* __restrict__ P,
                                                 const float* __restrict__ V,
                                                 float* __restrict__ O) {
    __shared__ float Ps[64][64];
    const int tid = threadIdx.x;
    const int bh = blockIdx.y;
    const int n = blockIdx.x * 256 + tid;
    const float* Pb = P + (size_t)bh * 4096;
#pragma unroll
    for (int r = 0; r < 4; ++r) {
        int id = tid + r * 256;
        int row = id >> 4;
        int col = (id & 15) << 2;
        *(float4*)&Ps[row][col] = *(const float4*)(Pb + row * 64 + col);
    }
    __syncthreads();
    float acc[64];
#pragma unroll
    for (int d = 0; d < 64; ++d) acc[d] = 0.f;
    const float* Vb = V + (size_t)bh * HDIM * NPIX + n;
#pragma unroll 1
    for (int e = 0; e < 64; ++e) {
        float vv = Vb[(size_t)e * NPIX];
#pragma unroll
        for (int d = 0; d < 64; ++d) acc[d] += Ps[d][e] * vv;
    }
    float* Ob = O + (size_t)bh * HDIM * NPIX + n;
#pragma unroll 1
    for (int d = 0; d < 64; ++d) Ob[(size_t)d * NPIX] = acc[d];
}

// ---------------------------------------------------------------------------
extern "C" void kernel_launch(void* const* d_in, const int* in_sizes, int n_in,
                              void* d_out, int out_size, void* d_ws, size_t ws_size,
                              hipStream_t stream) {
    (void)in_sizes; (void)n_in; (void)out_size; (void)ws_size;
    const float* x      = (const float*)d_in[0];
    const float* dw_w   = (const float*)d_in[1];
    const float* q_w    = (const float*)d_in[2];
    const float* k_w    = (const float*)d_in[3];
    const float* v_w    = (const float*)d_in[4];
    const float* proj_w = (const float*)d_in[5];
    float* out = (float*)d_out;

    const size_t SZ = (size_t)BATCH * CDIM * NPIX;   // 16,777,216 elements
    float* ws = (float*)d_ws;
    // region A [0, SZ): xd (fp32) -> q -> out2
    // region B [SZ, 1.5*SZ): xdT (bf16, SZ shorts) -> out2T
    // region K [1.5*SZ, 2.5*SZ): k
    // weights bf16 at 2.5*SZ (4 * 262144 shorts = 524288 floats)
    // norms (3*4096), Spart (16*4096*64), P (262144) after that
    float* A = ws;
    __hip_bfloat16* Bt = (__hip_bfloat16*)(ws + SZ);
    float* Kr = ws + SZ + SZ / 2;
    __hip_bfloat16* wqb = (__hip_bfloat16*)(ws + SZ + SZ / 2 + SZ);
    __hip_bfloat16* wkb = wqb + 262144;
    __hip_bfloat16* wvb = wkb + 262144;
    __hip_bfloat16* wpb = wvb + 262144;
    float* rq = (float*)(wpb + 262144);
    float* rk = rq + 4096;
    float* rv = rk + 4096;
    float* Spart = rv + 4096;                 // 4,194,304 floats
    float* P = Spart + (size_t)64 * 16 * 4096; // 262,144 floats

    float* xd   = A;
    float* q    = A;        // overwrites xd (dead after transpose)
    float* out2 = A;        // overwrites q  (dead after qk_partial)
    float* k    = Kr;
    float* v    = out;      // v lives in d_out; overwritten by proj at the end

    // 1) depthwise conv (fp32)
    dwconv3x3<<<dim3((BATCH * CDIM * NPIX) / 256), 256, 0, stream>>>(x, dw_w, xd);

    // 2) transpose+cast xd -> xdT bf16 [b][n][c]
    transpose_cast<<<dim3(NPIX / 64, CDIM / 64, BATCH), 256, 0, stream>>>(xd, Bt);

    // 3) cast weights to bf16
    cast_weights<<<dim3(262144 / 256, 4), 256, 0, stream>>>(q_w, k_w, v_w, proj_w,
                                                            wqb, wkb, wvb, wpb);

    // 4) q,k,v conv1x1 via bf16 MFMA GEMM
    dim3 gg(NPIX / 128, CDIM / 128, BATCH);
    gemm_bf16<<<gg, 256, 0, stream>>>(wqb, Bt, q);
    gemm_bf16<<<gg, 256, 0, stream>>>(wkb, Bt, k);
    gemm_bf16<<<gg, 256, 0, stream>>>(wvb, Bt, v);

    // 5) reciprocal L2 norms of each (b,h,d) row
    rownorm256<<<BATCH * CDIM, 256, 0, stream>>>(q, rq);
    rownorm256<<<BATCH * CDIM, 256, 0, stream>>>(k, rk);
    rownorm256<<<BATCH * CDIM, 256, 0, stream>>>(v, rv);

    // 6) chunked QK^T partials
    qk_partial<<<dim3(16, BATCH * NHEAD), 256, 0, stream>>>(q, k, Spart);

    // 7) softmax (+ fold in rq,rk,scale,rv)
    softmax_p<<<BATCH * NHEAD, 64, 0, stream>>>(Spart, rq, rk, rv, P);

    // 8) attention output (q region dead -> out2)
    pv_kernel<<<dim3(16, BATCH * NHEAD), 256, 0, stream>>>(P, v, out2);

    // 9) transpose+cast out2 -> out2T bf16 (xdT region dead)
    transpose_cast<<<dim3(NPIX / 64, CDIM / 64, BATCH), 256, 0, stream>>>(out2, Bt);

    // 10) projection conv1x1 (reads out2T, overwrites d_out which held v)
    gemm_bf16<<<gg, 256, 0, stream>>>(wpb, Bt, out);
}

// Round 4
// 407.053 us; speedup vs baseline: 3.7667x; 1.4447x over previous
//
#include <hip/hip_runtime.h>
#include <hip/hip_bf16.h>

// Problem constants (B=8, C=512, H=W=64, HEADS=8, HEAD_DIM=64)
#define BATCH 8
#define CDIM 512
#define NPIX 4096            // 64*64
#define NHEAD 8
#define HDIM 64
#define ATT_SCALE 0.125f     // HEAD_DIM^-0.5
#define L2EPS 1e-12f
#define KCH 8                // K-chunks for QK^T split (K=512 each)

typedef __attribute__((ext_vector_type(8))) short short8;   // 8 bf16 (4 VGPRs)
typedef __attribute__((ext_vector_type(4))) short bf16x4;   // 4 bf16 (8B)
typedef __attribute__((ext_vector_type(4))) float f32x4;    // MFMA C/D

typedef const __attribute__((address_space(1))) void* gas_ptr;
typedef __attribute__((address_space(3))) void* las_ptr;

__device__ __forceinline__ void ld_lds16(const void* g, void* l) {
    // async global->LDS, 16B/lane. LDS dest = wave-uniform base + lane*16.
    __builtin_amdgcn_global_load_lds((gas_ptr)g, (las_ptr)l, 16, 0, 0);
}

__device__ __forceinline__ short f2bs(float f) {
    __hip_bfloat16 h = __float2bfloat16(f);
    return *reinterpret_cast<short*>(&h);
}

// ---------------------------------------------------------------------------
// 1) fused depthwise 3x3 (pad 1) + transpose + bf16 cast.
//    x:[B,C,64,64] fp32 -> xdT:[B, N=4096, C=512] bf16.
//    grid (y=64, ctile=8, b=8), block 256. 64c x 64x tile via LDS.
// ---------------------------------------------------------------------------
__global__ __launch_bounds__(256) void dwconv_t(const float* __restrict__ x,
                                                const float* __restrict__ w,
                                                short* __restrict__ xdT) {
    __shared__ float tile[64][65];   // [c_local][x]
    const int t = threadIdx.x;
    const int y  = blockIdx.x;
    const int c0 = blockIdx.y * 64;
    const int b  = blockIdx.z;
    const int x_l = t & 63;
    const int c_sub = t >> 6;        // 0..3

#pragma unroll
    for (int i = 0; i < 16; ++i) {
        const int c_l = c_sub * 16 + i;
        const int c = c0 + c_l;
        const float* xp = x + ((size_t)(b * CDIM + c)) * NPIX;
        const float* wp = w + c * 9;
        float acc = 0.f;
#pragma unroll
        for (int dy = -1; dy <= 1; ++dy) {
            const int yy = y + dy;
            if (yy < 0 || yy > 63) continue;
            const float* rowp = xp + yy * 64;
#pragma unroll
            for (int dx = -1; dx <= 1; ++dx) {
                const int xx = x_l + dx;
                if (xx < 0 || xx > 63) continue;
                acc += wp[(dy + 1) * 3 + dx + 1] * rowp[xx];
            }
        }
        tile[c_l][x_l] = acc;
    }
    __syncthreads();
    // write phase: row n = y*64 + r  (r = t>>2), 16 channels per thread
    const int r = t >> 2;
    const int coff = (t & 3) * 16;
    __align__(16) short tmp[16];
#pragma unroll
    for (int i = 0; i < 16; ++i) tmp[i] = f2bs(tile[coff + i][r]);
    short* dst = xdT + ((size_t)b * NPIX + y * 64 + r) * CDIM + c0 + coff;
    *(short8*)dst = *(short8*)&tmp[0];
    *(short8*)(dst + 8) = *(short8*)&tmp[8];
}

// ---------------------------------------------------------------------------
// 2) cast the four 512x512 fp32 weight matrices to bf16
// ---------------------------------------------------------------------------
__global__ __launch_bounds__(256) void cast_weights(const float* __restrict__ s0,
                                                    const float* __restrict__ s1,
                                                    const float* __restrict__ s2,
                                                    const float* __restrict__ s3,
                                                    short* __restrict__ d0,
                                                    short* __restrict__ d1,
                                                    short* __restrict__ d2,
                                                    short* __restrict__ d3) {
    int i = blockIdx.x * 256 + threadIdx.x;   // 0..262143
    const float* s = (blockIdx.y == 0) ? s0 : (blockIdx.y == 1) ? s1 : (blockIdx.y == 2) ? s2 : s3;
    short* d = (blockIdx.y == 0) ? d0 : (blockIdx.y == 1) ? d1 : (blockIdx.y == 2) ? d2 : d3;
    d[i] = f2bs(s[i]);
}

// ---------------------------------------------------------------------------
// GEMM core macro parts: Y[b][o][n] = sum_c W[o][c] * X[b][n][c]^T
// W: [512][512] bf16 k-contig. XT: [b][4096][512] bf16 k-contig.
// 128x128 tile, 4 waves, 4x4 x mfma_f32_16x16x32_bf16. grid (32, 4, B).
// Three epilogue variants below share the same main loop.
// ---------------------------------------------------------------------------
#define GEMM_MAIN_LOOP                                                         \
    __shared__ __align__(16) short As[128 * 32];                               \
    __shared__ __align__(16) short Bs[128 * 32];                               \
    const int tid  = threadIdx.x;                                              \
    const int wave = tid >> 6;                                                 \
    const int lane = tid & 63;                                                 \
    const int n0 = blockIdx.x * 128;                                           \
    const int o0 = blockIdx.y * 128;                                           \
    const int b  = blockIdx.z;                                                 \
    const short* Wg = W + (size_t)o0 * CDIM;                                   \
    const short* Xg = XT + ((size_t)b * NPIX + n0) * CDIM;                     \
    const int am = (wave >> 1) * 64;                                           \
    const int bn = (wave & 1) * 64;                                            \
    const int lrow = lane & 15;                                                \
    const int lk   = (lane >> 4) * 8;                                          \
    f32x4 acc[4][4] = {};                                                      \
    for (int k0 = 0; k0 < CDIM; k0 += 32) {                                    \
        _Pragma("unroll")                                                      \
        for (int i = 0; i < 2; ++i) {                                          \
            const int q = i * 256 + wave * 64 + lane;                          \
            const int r = q >> 2;                                              \
            const int c = (q & 3) * 8;                                         \
            const int ldsoff = (i * 256 + wave * 64) * 8;                      \
            ld_lds16(Wg + (size_t)r * CDIM + k0 + c, As + ldsoff);             \
            ld_lds16(Xg + (size_t)r * CDIM + k0 + c, Bs + ldsoff);             \
        }                                                                      \
        __syncthreads();                                                       \
        short8 afrag[4], bfrag[4];                                             \
        _Pragma("unroll")                                                      \
        for (int i = 0; i < 4; ++i)                                            \
            afrag[i] = *(const short8*)&As[(am + i * 16 + lrow) * 32 + lk];    \
        _Pragma("unroll")                                                      \
        for (int j = 0; j < 4; ++j)                                            \
            bfrag[j] = *(const short8*)&Bs[(bn + j * 16 + lrow) * 32 + lk];    \
        _Pragma("unroll")                                                      \
        for (int i = 0; i < 4; ++i)                                            \
            _Pragma("unroll")                                                  \
            for (int j = 0; j < 4; ++j)                                        \
                acc[i][j] = __builtin_amdgcn_mfma_f32_16x16x32_bf16(           \
                    afrag[i], bfrag[j], acc[i][j], 0, 0, 0);                   \
        __syncthreads();                                                       \
    }                                                                          \
    const int crow = (lane >> 4) * 4;                                          \
    const int ccol = lane & 15;

// squared-row-sum epilogue: atomicAdd per-(b,c) row sums of acc^2 into SqDst
#define GEMM_SQ_EPILOGUE                                                       \
    {                                                                          \
        float sq[4][4];                                                        \
        _Pragma("unroll")                                                      \
        for (int i = 0; i < 4; ++i)                                            \
            _Pragma("unroll")                                                  \
            for (int r = 0; r < 4; ++r) {                                      \
                float s = 0.f;                                                 \
                _Pragma("unroll")                                              \
                for (int j = 0; j < 4; ++j) s += acc[i][j][r] * acc[i][j][r];  \
                s += __shfl_xor(s, 1); s += __shfl_xor(s, 2);                  \
                s += __shfl_xor(s, 4); s += __shfl_xor(s, 8);                  \
                sq[i][r] = s;                                                  \
            }                                                                  \
        if (ccol == 0) {                                                       \
            _Pragma("unroll")                                                  \
            for (int i = 0; i < 4; ++i)                                        \
                _Pragma("unroll")                                              \
                for (int r = 0; r < 4; ++r)                                    \
                    atomicAdd(SqDst + b * CDIM + o0 + am + i * 16 + crow + r,  \
                              sq[i][r]);                                       \
        }                                                                      \
    }

// variant A: bf16 output [b*512+o][n] (for q and k) + squared sums
__global__ __launch_bounds__(256) void gemm_qk(const short* __restrict__ W,
                                               const short* __restrict__ XT,
                                               short* __restrict__ Y,
                                               float* __restrict__ SqDst) {
    GEMM_MAIN_LOOP
    GEMM_SQ_EPILOGUE
#pragma unroll
    for (int i = 0; i < 4; ++i)
#pragma unroll
        for (int j = 0; j < 4; ++j)
#pragma unroll
            for (int r = 0; r < 4; ++r) {
                const int om = o0 + am + i * 16 + crow + r;
                const int on = n0 + bn + j * 16 + ccol;
                Y[((size_t)b * CDIM + om) * NPIX + on] = f2bs(acc[i][j][r]);
            }
}

// variant B: transposed bf16 output VT[b][n][c] (for v) + squared sums
__global__ __launch_bounds__(256) void gemm_vT(const short* __restrict__ W,
                                               const short* __restrict__ XT,
                                               short* __restrict__ VT,
                                               float* __restrict__ SqDst) {
    GEMM_MAIN_LOOP
    GEMM_SQ_EPILOGUE
#pragma unroll
    for (int i = 0; i < 4; ++i)
#pragma unroll
        for (int j = 0; j < 4; ++j) {
            const int om = o0 + am + i * 16 + crow;       // +r contiguous
            const int on = n0 + bn + j * 16 + ccol;
            bf16x4 pk;
#pragma unroll
            for (int r = 0; r < 4; ++r) pk[r] = f2bs(acc[i][j][r]);
            *(bf16x4*)&VT[((size_t)b * NPIX + on) * CDIM + om] = pk;
        }
}

// variant C: fp32 output [b][o][n] (for proj)
__global__ __launch_bounds__(256) void gemm_f32(const short* __restrict__ W,
                                                const short* __restrict__ XT,
                                                float* __restrict__ Y) {
    GEMM_MAIN_LOOP
    (void)crow;
#pragma unroll
    for (int i = 0; i < 4; ++i)
#pragma unroll
        for (int j = 0; j < 4; ++j)
#pragma unroll
            for (int r = 0; r < 4; ++r) {
                const int om = o0 + am + i * 16 + crow + r;
                const int on = n0 + bn + j * 16 + ccol;
                Y[((size_t)b * CDIM + om) * NPIX + on] = acc[i][j][r];
            }
}

// ---------------------------------------------------------------------------
// 3) QK^T partials via MFMA: Spart[kc][bh][d][e] = sum_{n in chunk} q[d,n]k[e,n]
//    q,k: bf16 [bh*64+d][4096] (k-contig). grid (KCH, 64 bh), block 256.
//    wave w computes d-strip [w*16, w*16+16) x all 64 e.
// ---------------------------------------------------------------------------
__global__ __launch_bounds__(256) void qk_mfma(const short* __restrict__ Q,
                                               const short* __restrict__ K,
                                               float* __restrict__ Spart) {
    __shared__ __align__(16) short Qs[64 * 32];
    __shared__ __align__(16) short Ks[64 * 32];
    const int tid = threadIdx.x;
    const int wave = tid >> 6;
    const int lane = tid & 63;
    const int kc = blockIdx.x;
    const int bh = blockIdx.y;
    const int kbase = kc * (NPIX / KCH);
    const short* qg = Q + (size_t)bh * HDIM * NPIX;
    const short* kg = K + (size_t)bh * HDIM * NPIX;
    const int lrow = lane & 15;
    const int lk = (lane >> 4) * 8;
    const int chunk = wave * 64 + lane;       // 0..255
    const int srow = chunk >> 2;              // 0..63
    const int scol = (chunk & 3) * 8;
    f32x4 acc[4] = {};
    for (int k0 = 0; k0 < NPIX / KCH; k0 += 32) {
        ld_lds16(qg + (size_t)srow * NPIX + kbase + k0 + scol, Qs + wave * 512);
        ld_lds16(kg + (size_t)srow * NPIX + kbase + k0 + scol, Ks + wave * 512);
        __syncthreads();
        short8 af = *(const short8*)&Qs[(wave * 16 + lrow) * 32 + lk];
#pragma unroll
        for (int j = 0; j < 4; ++j) {
            short8 bf = *(const short8*)&Ks[(j * 16 + lrow) * 32 + lk];
            acc[j] = __builtin_amdgcn_mfma_f32_16x16x32_bf16(af, bf, acc[j], 0, 0, 0);
        }
        __syncthreads();
    }
    float* sp = Spart + ((size_t)(kc * 64 + bh)) * 64 * 64;
    const int crow = (lane >> 4) * 4;
    const int ccol = lane & 15;
#pragma unroll
    for (int j = 0; j < 4; ++j)
#pragma unroll
        for (int r = 0; r < 4; ++r)
            sp[(wave * 16 + crow + r) * 64 + j * 16 + ccol] = acc[j][r];
}

// ---------------------------------------------------------------------------
// 4) reduce partials, apply norms+scale, softmax over e, fold rv; P bf16
// ---------------------------------------------------------------------------
__global__ __launch_bounds__(64) void softmax_p(const float* __restrict__ Spart,
                                                const float* __restrict__ Sq,
                                                short* __restrict__ P) {
    const int bh = blockIdx.x;
    const int d = threadIdx.x;    // 0..63
    __shared__ float rks[64], rvs[64];
    rks[d] = 1.0f / fmaxf(sqrtf(Sq[4096 + bh * 64 + d]), L2EPS);
    rvs[d] = 1.0f / fmaxf(sqrtf(Sq[8192 + bh * 64 + d]), L2EPS);
    __syncthreads();
    const float rqd = ATT_SCALE / fmaxf(sqrtf(Sq[bh * 64 + d]), L2EPS);
    float srow[64];
#pragma unroll
    for (int e = 0; e < 64; ++e) {
        float s = 0.f;
#pragma unroll
        for (int kc = 0; kc < KCH; ++kc)
            s += Spart[(((size_t)kc * 64 + bh) * 64 + d) * 64 + e];
        srow[e] = s * rqd * rks[e];
    }
    float m = -1e30f;
#pragma unroll
    for (int e = 0; e < 64; ++e) m = fmaxf(m, srow[e]);
    float sum = 0.f;
#pragma unroll
    for (int e = 0; e < 64; ++e) { float p = expf(srow[e] - m); srow[e] = p; sum += p; }
    const float inv = 1.f / sum;
    short* pp = P + (size_t)bh * 4096 + d * 64;
#pragma unroll
    for (int e = 0; e < 64; ++e) pp[e] = f2bs(srow[e] * inv * rvs[e]);
}

// ---------------------------------------------------------------------------
// 5) PV via MFMA: OT[b][n][h*64+d] = sum_e P[bh][d][e] * VT[b][n][h*64+e]
//    A = P (m=d, k=e), B = VT rows (n'=n, k=e). grid (16 nchunks, 64 bh).
//    wave w handles n-strip [w*64, (w+1)*64). K=64 staged once.
// ---------------------------------------------------------------------------
__global__ __launch_bounds__(256) void pv_mfma(const short* __restrict__ P,
                                               const short* __restrict__ VT,
                                               short* __restrict__ OT) {
    __shared__ __align__(16) short Ps[64 * 64];    // 8 KB
    __shared__ __align__(16) short Vs[256 * 64];   // 32 KB
    const int tid = threadIdx.x;
    const int wave = tid >> 6;
    const int lane = tid & 63;
    const int nc = blockIdx.x;
    const int bh = blockIdx.y;
    const int b = bh >> 3, h = bh & 7;
    const int n0 = nc * 256;
    // stage P: 512 x 16B chunks (rows of 8 chunks)
#pragma unroll
    for (int i = 0; i < 2; ++i) {
        const int cb = i * 256 + wave * 64;
        const int chunk = cb + lane;
        ld_lds16(P + (size_t)bh * 4096 + (chunk >> 3) * 64 + (chunk & 7) * 8,
                 Ps + cb * 8);
    }
    // stage V^T tile: 2048 x 16B chunks
#pragma unroll
    for (int i = 0; i < 8; ++i) {
        const int cb = i * 256 + wave * 64;
        const int chunk = cb + lane;
        ld_lds16(VT + ((size_t)b * NPIX + n0 + (chunk >> 3)) * CDIM + h * 64 + (chunk & 7) * 8,
                 Vs + cb * 8);
    }
    __syncthreads();
    const int lrow = lane & 15;
    const int lq = (lane >> 4) * 8;
    f32x4 acc[4][4] = {};
#pragma unroll
    for (int ks = 0; ks < 2; ++ks) {
        const int ko = ks * 32 + lq;
        short8 af[4], bf[4];
#pragma unroll
        for (int i = 0; i < 4; ++i)
            af[i] = *(const short8*)&Ps[(i * 16 + lrow) * 64 + ko];
#pragma unroll
        for (int j = 0; j < 4; ++j)
            bf[j] = *(const short8*)&Vs[(wave * 64 + j * 16 + lrow) * 64 + ko];
#pragma unroll
        for (int i = 0; i < 4; ++i)
#pragma unroll
            for (int j = 0; j < 4; ++j)
                acc[i][j] = __builtin_amdgcn_mfma_f32_16x16x32_bf16(af[i], bf[j],
                                                                   acc[i][j], 0, 0, 0);
    }
    const int crow = (lane >> 4) * 4;
    const int ccol = lane & 15;
#pragma unroll
    for (int i = 0; i < 4; ++i)
#pragma unroll
        for (int j = 0; j < 4; ++j) {
            const int n = n0 + wave * 64 + j * 16 + ccol;
            const int c = h * 64 + i * 16 + crow;     // +r contiguous
            bf16x4 pk;
#pragma unroll
            for (int r = 0; r < 4; ++r) pk[r] = f2bs(acc[i][j][r]);
            *(bf16x4*)&OT[((size_t)b * NPIX + n) * CDIM + c] = pk;
        }
}

// ---------------------------------------------------------------------------
extern "C" void kernel_launch(void* const* d_in, const int* in_sizes, int n_in,
                              void* d_out, int out_size, void* d_ws, size_t ws_size,
                              hipStream_t stream) {
    (void)in_sizes; (void)n_in; (void)out_size; (void)ws_size;
    const float* x      = (const float*)d_in[0];
    const float* dw_w   = (const float*)d_in[1];
    const float* q_w    = (const float*)d_in[2];
    const float* k_w    = (const float*)d_in[3];
    const float* v_w    = (const float*)d_in[4];
    const float* proj_w = (const float*)d_in[5];
    float* out = (float*)d_out;

    const size_t SZ = (size_t)BATCH * CDIM * NPIX;   // 16,777,216 elements
    float* ws = (float*)d_ws;
    // ws layout (floats). Peak usage = 3*SZ = 201.3 MB (proven fit in R1).
    //   [0, SZ/2):        OT bf16 (SZ shorts) + (disjoint, above OT) Spart/Sq/P/weights
    //   [SZ, 1.5SZ):      xdT bf16
    //   [1.5SZ, 2SZ):     q bf16
    //   [2SZ, 2.5SZ):     k bf16
    //   [2.5SZ, 3SZ):     VT bf16
    short* OT  = (short*)ws;                               // SZ shorts
    float* Spart = ws + SZ / 2;                            // KCH*64*64*64 = 2,097,152 fl
    float* Sq    = Spart + (size_t)KCH * 64 * 64 * 64;     // 3*4096 fl (SqQ,SqK,SqV)
    short* Pb    = (short*)(Sq + 3 * 4096);                // 262,144 shorts
    short* wqb   = Pb + 262144;                            // 4 x 262,144 shorts
    short* wkb   = wqb + 262144;
    short* wvb   = wkb + 262144;
    short* wpb   = wvb + 262144;
    short* xdT = (short*)(ws + SZ);
    short* qb  = (short*)(ws + SZ + SZ / 2);
    short* kb  = (short*)(ws + 2 * SZ);
    short* vT  = (short*)(ws + 2 * SZ + SZ / 2);

    // 0) zero the squared-norm accumulators
    (void)hipMemsetAsync(Sq, 0, 3 * 4096 * sizeof(float), stream);

    // 1) fused dwconv3x3 + transpose + bf16 cast -> xdT
    dwconv_t<<<dim3(64, 8, BATCH), 256, 0, stream>>>(x, dw_w, xdT);

    // 2) weights -> bf16
    cast_weights<<<dim3(262144 / 256, 4), 256, 0, stream>>>(q_w, k_w, v_w, proj_w,
                                                            wqb, wkb, wvb, wpb);

    // 3) q,k,v GEMMs (bf16 out, fused squared-row-sums)
    dim3 gg(NPIX / 128, CDIM / 128, BATCH);
    gemm_qk<<<gg, 256, 0, stream>>>(wqb, xdT, qb, Sq);
    gemm_qk<<<gg, 256, 0, stream>>>(wkb, xdT, kb, Sq + 4096);
    gemm_vT<<<gg, 256, 0, stream>>>(wvb, xdT, vT, Sq + 8192);

    // 4) QK^T partials via MFMA
    qk_mfma<<<dim3(KCH, BATCH * NHEAD), 256, 0, stream>>>(qb, kb, Spart);

    // 5) softmax (+ norms + scale + rv folded), P bf16
    softmax_p<<<BATCH * NHEAD, 64, 0, stream>>>(Spart, Sq, Pb);

    // 6) PV via MFMA -> OT bf16 [b][n][c] (proj input layout)
    pv_mfma<<<dim3(16, BATCH * NHEAD), 256, 0, stream>>>(Pb, vT, OT);

    // 7) projection conv1x1 -> fp32 out
    gemm_f32<<<gg, 256, 0, stream>>>(wpb, OT, out);
}

// Round 5
// 329.962 us; speedup vs baseline: 4.6468x; 1.2336x over previous
//
#include <hip/hip_runtime.h>
#include <hip/hip_bf16.h>

// Problem constants (B=8, C=512, H=W=64, HEADS=8, HEAD_DIM=64)
#define BATCH 8
#define CDIM 512
#define NPIX 4096            // 64*64
#define NHEAD 8
#define HDIM 64
#define ATT_SCALE 0.125f     // HEAD_DIM^-0.5
#define L2EPS 1e-12f
#define KCH 8                // K-chunks for QK^T split (K=512 each)
#define STRIP 8              // y-rows per dwconv block

typedef __attribute__((ext_vector_type(8))) short short8;   // 8 bf16 (4 VGPRs)
typedef __attribute__((ext_vector_type(4))) short bf16x4;   // 4 bf16 (8B)
typedef __attribute__((ext_vector_type(4))) float f32x4;    // MFMA C/D

typedef const __attribute__((address_space(1))) void* gas_ptr;
typedef __attribute__((address_space(3))) void* las_ptr;

__device__ __forceinline__ void ld_lds16(const void* g, void* l) {
    // async global->LDS, 16B/lane. LDS dest = wave-uniform base + lane*16.
    __builtin_amdgcn_global_load_lds((gas_ptr)g, (las_ptr)l, 16, 0, 0);
}

__device__ __forceinline__ short f2bs(float f) {
    __hip_bfloat16 h = __float2bfloat16(f);
    return *reinterpret_cast<short*>(&h);
}

// ---------------------------------------------------------------------------
// 1) fused depthwise 3x3 (pad 1) + transpose + bf16 cast, v2.
//    x:[B,C,64,64] fp32 -> xdT:[B, N=4096, C=512] bf16.
//    grid (8 y-strips, 32 c-tiles of 16, B), block 256.
//    lane = x column (wave spans one image row); thread owns 4 channels;
//    sliding 3-row register window; horizontal taps via 2 shuffles.
// ---------------------------------------------------------------------------
__global__ __launch_bounds__(256) void dwconv_t(const float* __restrict__ x,
                                                const float* __restrict__ w,
                                                short* __restrict__ xdT) {
    __shared__ float tile[16][65];   // [c_local][x], 2-way bank alias (free)
    const int t = threadIdx.x;
    const int lane = t & 63;          // x coordinate
    const int wv = t >> 6;            // 0..3
    const int y0 = blockIdx.x * STRIP;
    const int c0 = blockIdx.y * 16;
    const int b  = blockIdx.z;

    float wgt[4][9];
    float r0[4], r1[4], r2[4];
    const float* xb[4];
#pragma unroll
    for (int i = 0; i < 4; ++i) {
        const int c = c0 + wv * 4 + i;
        const float* wp = w + c * 9;
#pragma unroll
        for (int j = 0; j < 9; ++j) wgt[i][j] = wp[j];
        xb[i] = x + ((size_t)(b * CDIM + c)) * NPIX + lane;
        r0[i] = (y0 > 0) ? xb[i][(y0 - 1) * 64] : 0.f;
        r1[i] = xb[i][y0 * 64];
        r2[i] = xb[i][(y0 + 1) * 64];     // y0+1 <= 57 < 64 always
    }

    for (int yy = 0; yy < STRIP; ++yy) {
        const int ynext = y0 + yy + 2;
        const bool ldn = (yy < STRIP - 1) && (ynext < 64);
        float nxt[4];
#pragma unroll
        for (int i = 0; i < 4; ++i) nxt[i] = ldn ? xb[i][ynext * 64] : 0.f;

#pragma unroll
        for (int i = 0; i < 4; ++i) {
            // column sums: weights col dx=-1 -> {0,3,6}, dx=0 -> {1,4,7}, dx=+1 -> {2,5,8}
            float cl = wgt[i][0] * r0[i] + wgt[i][3] * r1[i] + wgt[i][6] * r2[i];
            float cm = wgt[i][1] * r0[i] + wgt[i][4] * r1[i] + wgt[i][7] * r2[i];
            float cr = wgt[i][2] * r0[i] + wgt[i][5] * r1[i] + wgt[i][8] * r2[i];
            float lft = __shfl_up(cl, 1);     // lane x <- cl[x-1]
            if (lane == 0) lft = 0.f;
            float rgt = __shfl_down(cr, 1);   // lane x <- cr[x+1]
            if (lane == 63) rgt = 0.f;
            tile[wv * 4 + i][lane] = lft + cm + rgt;
        }
        __syncthreads();
        // transpose-write this y row: n = (y0+yy)*64 + n_l
        {
            const int n_l = t >> 2;
            const int cq = (t & 3) * 4;
            bf16x4 pk;
#pragma unroll
            for (int j = 0; j < 4; ++j) pk[j] = f2bs(tile[cq + j][n_l]);
            short* dst = xdT + ((size_t)b * NPIX + (y0 + yy) * 64 + n_l) * CDIM + c0 + cq;
            *(bf16x4*)dst = pk;
        }
        __syncthreads();
#pragma unroll
        for (int i = 0; i < 4; ++i) { r0[i] = r1[i]; r1[i] = r2[i]; r2[i] = nxt[i]; }
    }
}

// ---------------------------------------------------------------------------
// 2) cast the four 512x512 fp32 weight matrices to bf16
// ---------------------------------------------------------------------------
__global__ __launch_bounds__(256) void cast_weights(const float* __restrict__ s0,
                                                    const float* __restrict__ s1,
                                                    const float* __restrict__ s2,
                                                    const float* __restrict__ s3,
                                                    short* __restrict__ d0,
                                                    short* __restrict__ d1,
                                                    short* __restrict__ d2,
                                                    short* __restrict__ d3) {
    int i = blockIdx.x * 256 + threadIdx.x;   // 0..262143
    const float* s = (blockIdx.y == 0) ? s0 : (blockIdx.y == 1) ? s1 : (blockIdx.y == 2) ? s2 : s3;
    short* d = (blockIdx.y == 0) ? d0 : (blockIdx.y == 1) ? d1 : (blockIdx.y == 2) ? d2 : d3;
    d[i] = f2bs(s[i]);
}

// ---------------------------------------------------------------------------
// GEMM core macro parts: Y[b][o][n] = sum_c W[o][c] * X[b][n][c]^T
// W: [512][512] bf16 k-contig. XT: [b][4096][512] bf16 k-contig.
// 128x128 tile, 4 waves, 4x4 x mfma_f32_16x16x32_bf16. grid (32, 4, B).
// ---------------------------------------------------------------------------
#define GEMM_MAIN_LOOP                                                         \
    __shared__ __align__(16) short As[128 * 32];                               \
    __shared__ __align__(16) short Bs[128 * 32];                               \
    const int tid  = threadIdx.x;                                              \
    const int wave = tid >> 6;                                                 \
    const int lane = tid & 63;                                                 \
    const int n0 = blockIdx.x * 128;                                           \
    const int o0 = blockIdx.y * 128;                                           \
    const int b  = blockIdx.z;                                                 \
    const short* Wg = W + (size_t)o0 * CDIM;                                   \
    const short* Xg = XT + ((size_t)b * NPIX + n0) * CDIM;                     \
    const int am = (wave >> 1) * 64;                                           \
    const int bn = (wave & 1) * 64;                                            \
    const int lrow = lane & 15;                                                \
    const int lk   = (lane >> 4) * 8;                                          \
    f32x4 acc[4][4] = {};                                                      \
    for (int k0 = 0; k0 < CDIM; k0 += 32) {                                    \
        _Pragma("unroll")                                                      \
        for (int i = 0; i < 2; ++i) {                                          \
            const int q = i * 256 + wave * 64 + lane;                          \
            const int r = q >> 2;                                              \
            const int c = (q & 3) * 8;                                         \
            const int ldsoff = (i * 256 + wave * 64) * 8;                      \
            ld_lds16(Wg + (size_t)r * CDIM + k0 + c, As + ldsoff);             \
            ld_lds16(Xg + (size_t)r * CDIM + k0 + c, Bs + ldsoff);             \
        }                                                                      \
        __syncthreads();                                                       \
        short8 afrag[4], bfrag[4];                                             \
        _Pragma("unroll")                                                      \
        for (int i = 0; i < 4; ++i)                                            \
            afrag[i] = *(const short8*)&As[(am + i * 16 + lrow) * 32 + lk];    \
        _Pragma("unroll")                                                      \
        for (int j = 0; j < 4; ++j)                                            \
            bfrag[j] = *(const short8*)&Bs[(bn + j * 16 + lrow) * 32 + lk];    \
        _Pragma("unroll")                                                      \
        for (int i = 0; i < 4; ++i)                                            \
            _Pragma("unroll")                                                  \
            for (int j = 0; j < 4; ++j)                                        \
                acc[i][j] = __builtin_amdgcn_mfma_f32_16x16x32_bf16(           \
                    afrag[i], bfrag[j], acc[i][j], 0, 0, 0);                   \
        __syncthreads();                                                       \
    }                                                                          \
    const int crow = (lane >> 4) * 4;                                          \
    const int ccol = lane & 15;

// squared-row-sum epilogue: atomicAdd per-(b,c) row sums of acc^2 into SqDst
#define GEMM_SQ_EPILOGUE                                                       \
    {                                                                          \
        float sq[4][4];                                                        \
        _Pragma("unroll")                                                      \
        for (int i = 0; i < 4; ++i)                                            \
            _Pragma("unroll")                                                  \
            for (int r = 0; r < 4; ++r) {                                      \
                float s = 0.f;                                                 \
                _Pragma("unroll")                                              \
                for (int j = 0; j < 4; ++j) s += acc[i][j][r] * acc[i][j][r];  \
                s += __shfl_xor(s, 1); s += __shfl_xor(s, 2);                  \
                s += __shfl_xor(s, 4); s += __shfl_xor(s, 8);                  \
                sq[i][r] = s;                                                  \
            }                                                                  \
        if (ccol == 0) {                                                       \
            _Pragma("unroll")                                                  \
            for (int i = 0; i < 4; ++i)                                        \
                _Pragma("unroll")                                              \
                for (int r = 0; r < 4; ++r)                                    \
                    atomicAdd(SqDst + b * CDIM + o0 + am + i * 16 + crow + r,  \
                              sq[i][r]);                                       \
        }                                                                      \
    }

// variant A: bf16 output [b*512+o][n] (for q and k) + squared sums
__global__ __launch_bounds__(256) void gemm_qk(const short* __restrict__ W,
                                               const short* __restrict__ XT,
                                               short* __restrict__ Y,
                                               float* __restrict__ SqDst) {
    GEMM_MAIN_LOOP
    GEMM_SQ_EPILOGUE
#pragma unroll
    for (int i = 0; i < 4; ++i)
#pragma unroll
        for (int j = 0; j < 4; ++j)
#pragma unroll
            for (int r = 0; r < 4; ++r) {
                const int om = o0 + am + i * 16 + crow + r;
                const int on = n0 + bn + j * 16 + ccol;
                Y[((size_t)b * CDIM + om) * NPIX + on] = f2bs(acc[i][j][r]);
            }
}

// variant B: transposed bf16 output VT[b][n][c] (for v) + squared sums
__global__ __launch_bounds__(256) void gemm_vT(const short* __restrict__ W,
                                               const short* __restrict__ XT,
                                               short* __restrict__ VT,
                                               float* __restrict__ SqDst) {
    GEMM_MAIN_LOOP
    GEMM_SQ_EPILOGUE
#pragma unroll
    for (int i = 0; i < 4; ++i)
#pragma unroll
        for (int j = 0; j < 4; ++j) {
            const int om = o0 + am + i * 16 + crow;       // +r contiguous
            const int on = n0 + bn + j * 16 + ccol;
            bf16x4 pk;
#pragma unroll
            for (int r = 0; r < 4; ++r) pk[r] = f2bs(acc[i][j][r]);
            *(bf16x4*)&VT[((size_t)b * NPIX + on) * CDIM + om] = pk;
        }
}

// variant C: fp32 output [b][o][n] (for proj)
__global__ __launch_bounds__(256) void gemm_f32(const short* __restrict__ W,
                                                const short* __restrict__ XT,
                                                float* __restrict__ Y) {
    GEMM_MAIN_LOOP
    (void)crow;
#pragma unroll
    for (int i = 0; i < 4; ++i)
#pragma unroll
        for (int j = 0; j < 4; ++j)
#pragma unroll
            for (int r = 0; r < 4; ++r) {
                const int om = o0 + am + i * 16 + crow + r;
                const int on = n0 + bn + j * 16 + ccol;
                Y[((size_t)b * CDIM + om) * NPIX + on] = acc[i][j][r];
            }
}

// ---------------------------------------------------------------------------
// 3) QK^T partials via MFMA: Spart[kc][bh][d][e] = sum_{n in chunk} q[d,n]k[e,n]
// ---------------------------------------------------------------------------
__global__ __launch_bounds__(256) void qk_mfma(const short* __restrict__ Q,
                                               const short* __restrict__ K,
                                               float* __restrict__ Spart) {
    __shared__ __align__(16) short Qs[64 * 32];
    __shared__ __align__(16) short Ks[64 * 32];
    const int tid = threadIdx.x;
    const int wave = tid >> 6;
    const int lane = tid & 63;
    const int kc = blockIdx.x;
    const int bh = blockIdx.y;
    const int kbase = kc * (NPIX / KCH);
    const short* qg = Q + (size_t)bh * HDIM * NPIX;
    const short* kg = K + (size_t)bh * HDIM * NPIX;
    const int lrow = lane & 15;
    const int lk = (lane >> 4) * 8;
    const int chunk = wave * 64 + lane;       // 0..255
    const int srow = chunk >> 2;              // 0..63
    const int scol = (chunk & 3) * 8;
    f32x4 acc[4] = {};
    for (int k0 = 0; k0 < NPIX / KCH; k0 += 32) {
        ld_lds16(qg + (size_t)srow * NPIX + kbase + k0 + scol, Qs + wave * 512);
        ld_lds16(kg + (size_t)srow * NPIX + kbase + k0 + scol, Ks + wave * 512);
        __syncthreads();
        short8 af = *(const short8*)&Qs[(wave * 16 + lrow) * 32 + lk];
#pragma unroll
        for (int j = 0; j < 4; ++j) {
            short8 bf = *(const short8*)&Ks[(j * 16 + lrow) * 32 + lk];
            acc[j] = __builtin_amdgcn_mfma_f32_16x16x32_bf16(af, bf, acc[j], 0, 0, 0);
        }
        __syncthreads();
    }
    float* sp = Spart + ((size_t)(kc * 64 + bh)) * 64 * 64;
    const int crow = (lane >> 4) * 4;
    const int ccol = lane & 15;
#pragma unroll
    for (int j = 0; j < 4; ++j)
#pragma unroll
        for (int r = 0; r < 4; ++r)
            sp[(wave * 16 + crow + r) * 64 + j * 16 + ccol] = acc[j][r];
}

// ---------------------------------------------------------------------------
// 4) reduce partials, apply norms+scale, softmax over e, fold rv; P bf16
// ---------------------------------------------------------------------------
__global__ __launch_bounds__(64) void softmax_p(const float* __restrict__ Spart,
                                                const float* __restrict__ Sq,
                                                short* __restrict__ P) {
    const int bh = blockIdx.x;
    const int d = threadIdx.x;    // 0..63
    __shared__ float rks[64], rvs[64];
    rks[d] = 1.0f / fmaxf(sqrtf(Sq[4096 + bh * 64 + d]), L2EPS);
    rvs[d] = 1.0f / fmaxf(sqrtf(Sq[8192 + bh * 64 + d]), L2EPS);
    __syncthreads();
    const float rqd = ATT_SCALE / fmaxf(sqrtf(Sq[bh * 64 + d]), L2EPS);
    float srow[64];
#pragma unroll
    for (int e = 0; e < 64; ++e) {
        float s = 0.f;
#pragma unroll
        for (int kc = 0; kc < KCH; ++kc)
            s += Spart[(((size_t)kc * 64 + bh) * 64 + d) * 64 + e];
        srow[e] = s * rqd * rks[e];
    }
    float m = -1e30f;
#pragma unroll
    for (int e = 0; e < 64; ++e) m = fmaxf(m, srow[e]);
    float sum = 0.f;
#pragma unroll
    for (int e = 0; e < 64; ++e) { float p = expf(srow[e] - m); srow[e] = p; sum += p; }
    const float inv = 1.f / sum;
    short* pp = P + (size_t)bh * 4096 + d * 64;
#pragma unroll
    for (int e = 0; e < 64; ++e) pp[e] = f2bs(srow[e] * inv * rvs[e]);
}

// ---------------------------------------------------------------------------
// 5) PV via MFMA: OT[b][n][h*64+d] = sum_e P[bh][d][e] * VT[b][n][h*64+e]
// ---------------------------------------------------------------------------
__global__ __launch_bounds__(256) void pv_mfma(const short* __restrict__ P,
                                               const short* __restrict__ VT,
                                               short* __restrict__ OT) {
    __shared__ __align__(16) short Ps[64 * 64];    // 8 KB
    __shared__ __align__(16) short Vs[256 * 64];   // 32 KB
    const int tid = threadIdx.x;
    const int wave = tid >> 6;
    const int lane = tid & 63;
    const int nc = blockIdx.x;
    const int bh = blockIdx.y;
    const int b = bh >> 3, h = bh & 7;
    const int n0 = nc * 256;
#pragma unroll
    for (int i = 0; i < 2; ++i) {
        const int cb = i * 256 + wave * 64;
        const int chunk = cb + lane;
        ld_lds16(P + (size_t)bh * 4096 + (chunk >> 3) * 64 + (chunk & 7) * 8,
                 Ps + cb * 8);
    }
#pragma unroll
    for (int i = 0; i < 8; ++i) {
        const int cb = i * 256 + wave * 64;
        const int chunk = cb + lane;
        ld_lds16(VT + ((size_t)b * NPIX + n0 + (chunk >> 3)) * CDIM + h * 64 + (chunk & 7) * 8,
                 Vs + cb * 8);
    }
    __syncthreads();
    const int lrow = lane & 15;
    const int lq = (lane >> 4) * 8;
    f32x4 acc[4][4] = {};
#pragma unroll
    for (int ks = 0; ks < 2; ++ks) {
        const int ko = ks * 32 + lq;
        short8 af[4], bf[4];
#pragma unroll
        for (int i = 0; i < 4; ++i)
            af[i] = *(const short8*)&Ps[(i * 16 + lrow) * 64 + ko];
#pragma unroll
        for (int j = 0; j < 4; ++j)
            bf[j] = *(const short8*)&Vs[(wave * 64 + j * 16 + lrow) * 64 + ko];
#pragma unroll
        for (int i = 0; i < 4; ++i)
#pragma unroll
            for (int j = 0; j < 4; ++j)
                acc[i][j] = __builtin_amdgcn_mfma_f32_16x16x32_bf16(af[i], bf[j],
                                                                   acc[i][j], 0, 0, 0);
    }
    const int crow = (lane >> 4) * 4;
    const int ccol = lane & 15;
#pragma unroll
    for (int i = 0; i < 4; ++i)
#pragma unroll
        for (int j = 0; j < 4; ++j) {
            const int n = n0 + wave * 64 + j * 16 + ccol;
            const int c = h * 64 + i * 16 + crow;     // +r contiguous
            bf16x4 pk;
#pragma unroll
            for (int r = 0; r < 4; ++r) pk[r] = f2bs(acc[i][j][r]);
            *(bf16x4*)&OT[((size_t)b * NPIX + n) * CDIM + c] = pk;
        }
}

// ---------------------------------------------------------------------------
extern "C" void kernel_launch(void* const* d_in, const int* in_sizes, int n_in,
                              void* d_out, int out_size, void* d_ws, size_t ws_size,
                              hipStream_t stream) {
    (void)in_sizes; (void)n_in; (void)out_size; (void)ws_size;
    const float* x      = (const float*)d_in[0];
    const float* dw_w   = (const float*)d_in[1];
    const float* q_w    = (const float*)d_in[2];
    const float* k_w    = (const float*)d_in[3];
    const float* v_w    = (const float*)d_in[4];
    const float* proj_w = (const float*)d_in[5];
    float* out = (float*)d_out;

    const size_t SZ = (size_t)BATCH * CDIM * NPIX;   // 16,777,216 elements
    float* ws = (float*)d_ws;
    short* OT  = (short*)ws;                               // SZ shorts
    float* Spart = ws + SZ / 2;                            // KCH*64*64*64 floats
    float* Sq    = Spart + (size_t)KCH * 64 * 64 * 64;     // 3*4096 fl (SqQ,SqK,SqV)
    short* Pb    = (short*)(Sq + 3 * 4096);                // 262,144 shorts
    short* wqb   = Pb + 262144;                            // 4 x 262,144 shorts
    short* wkb   = wqb + 262144;
    short* wvb   = wkb + 262144;
    short* wpb   = wvb + 262144;
    short* xdT = (short*)(ws + SZ);
    short* qb  = (short*)(ws + SZ + SZ / 2);
    short* kb  = (short*)(ws + 2 * SZ);
    short* vT  = (short*)(ws + 2 * SZ + SZ / 2);

    // 0) zero the squared-norm accumulators
    (void)hipMemsetAsync(Sq, 0, 3 * 4096 * sizeof(float), stream);

    // 1) fused dwconv3x3 + transpose + bf16 cast -> xdT (v2: register window)
    dwconv_t<<<dim3(64 / STRIP, CDIM / 16, BATCH), 256, 0, stream>>>(x, dw_w, xdT);

    // 2) weights -> bf16
    cast_weights<<<dim3(262144 / 256, 4), 256, 0, stream>>>(q_w, k_w, v_w, proj_w,
                                                            wqb, wkb, wvb, wpb);

    // 3) q,k,v GEMMs (bf16 out, fused squared-row-sums)
    dim3 gg(NPIX / 128, CDIM / 128, BATCH);
    gemm_qk<<<gg, 256, 0, stream>>>(wqb, xdT, qb, Sq);
    gemm_qk<<<gg, 256, 0, stream>>>(wkb, xdT, kb, Sq + 4096);
    gemm_vT<<<gg, 256, 0, stream>>>(wvb, xdT, vT, Sq + 8192);

    // 4) QK^T partials via MFMA
    qk_mfma<<<dim3(KCH, BATCH * NHEAD), 256, 0, stream>>>(qb, kb, Spart);

    // 5) softmax (+ norms + scale + rv folded), P bf16
    softmax_p<<<BATCH * NHEAD, 64, 0, stream>>>(Spart, Sq, Pb);

    // 6) PV via MFMA -> OT bf16 [b][n][c] (proj input layout)
    pv_mfma<<<dim3(16, BATCH * NHEAD), 256, 0, stream>>>(Pb, vT, OT);

    // 7) projection conv1x1 -> fp32 out
    gemm_f32<<<gg, 256, 0, stream>>>(wpb, OT, out);
}

// Round 6
// 324.435 us; speedup vs baseline: 4.7259x; 1.0170x over previous
//
#include <hip/hip_runtime.h>
#include <hip/hip_bf16.h>

// Problem constants (B=8, C=512, H=W=64, HEADS=8, HEAD_DIM=64)
#define BATCH 8
#define CDIM 512
#define NPIX 4096            // 64*64
#define NHEAD 8
#define HDIM 64
#define ATT_SCALE 0.125f     // HEAD_DIM^-0.5
#define L2EPS 1e-12f
#define KCH 8                // K-chunks for QK^T split (K=512 each)
#define STRIP 8              // y-rows per dwconv block

typedef __attribute__((ext_vector_type(8))) short short8;   // 8 bf16 (4 VGPRs)
typedef __attribute__((ext_vector_type(4))) short bf16x4;   // 4 bf16 (8B)
typedef __attribute__((ext_vector_type(4))) float f32x4;    // MFMA C/D

typedef const __attribute__((address_space(1))) void* gas_ptr;
typedef __attribute__((address_space(3))) void* las_ptr;

__device__ __forceinline__ void ld_lds16(const void* g, void* l) {
    // async global->LDS, 16B/lane. LDS dest = wave-uniform base + lane*16.
    __builtin_amdgcn_global_load_lds((gas_ptr)g, (las_ptr)l, 16, 0, 0);
}

__device__ __forceinline__ short f2bs(float f) {
    __hip_bfloat16 h = __float2bfloat16(f);
    return *reinterpret_cast<short*>(&h);
}

// ---------------------------------------------------------------------------
// 1) fused depthwise 3x3 (pad 1) + transpose + bf16 cast (register window).
// ---------------------------------------------------------------------------
__global__ __launch_bounds__(256) void dwconv_t(const float* __restrict__ x,
                                                const float* __restrict__ w,
                                                short* __restrict__ xdT) {
    __shared__ float tile[16][65];
    const int t = threadIdx.x;
    const int lane = t & 63;          // x coordinate
    const int wv = t >> 6;            // 0..3
    const int y0 = blockIdx.x * STRIP;
    const int c0 = blockIdx.y * 16;
    const int b  = blockIdx.z;

    float wgt[4][9];
    float r0[4], r1[4], r2[4];
    const float* xb[4];
#pragma unroll
    for (int i = 0; i < 4; ++i) {
        const int c = c0 + wv * 4 + i;
        const float* wp = w + c * 9;
#pragma unroll
        for (int j = 0; j < 9; ++j) wgt[i][j] = wp[j];
        xb[i] = x + ((size_t)(b * CDIM + c)) * NPIX + lane;
        r0[i] = (y0 > 0) ? xb[i][(y0 - 1) * 64] : 0.f;
        r1[i] = xb[i][y0 * 64];
        r2[i] = xb[i][(y0 + 1) * 64];
    }

    for (int yy = 0; yy < STRIP; ++yy) {
        const int ynext = y0 + yy + 2;
        const bool ldn = (yy < STRIP - 1) && (ynext < 64);
        float nxt[4];
#pragma unroll
        for (int i = 0; i < 4; ++i) nxt[i] = ldn ? xb[i][ynext * 64] : 0.f;

#pragma unroll
        for (int i = 0; i < 4; ++i) {
            float cl = wgt[i][0] * r0[i] + wgt[i][3] * r1[i] + wgt[i][6] * r2[i];
            float cm = wgt[i][1] * r0[i] + wgt[i][4] * r1[i] + wgt[i][7] * r2[i];
            float cr = wgt[i][2] * r0[i] + wgt[i][5] * r1[i] + wgt[i][8] * r2[i];
            float lft = __shfl_up(cl, 1);
            if (lane == 0) lft = 0.f;
            float rgt = __shfl_down(cr, 1);
            if (lane == 63) rgt = 0.f;
            tile[wv * 4 + i][lane] = lft + cm + rgt;
        }
        __syncthreads();
        {
            const int n_l = t >> 2;
            const int cq = (t & 3) * 4;
            bf16x4 pk;
#pragma unroll
            for (int j = 0; j < 4; ++j) pk[j] = f2bs(tile[cq + j][n_l]);
            short* dst = xdT + ((size_t)b * NPIX + (y0 + yy) * 64 + n_l) * CDIM + c0 + cq;
            *(bf16x4*)dst = pk;
        }
        __syncthreads();
#pragma unroll
        for (int i = 0; i < 4; ++i) { r0[i] = r1[i]; r1[i] = r2[i]; r2[i] = nxt[i]; }
    }
}

// ---------------------------------------------------------------------------
// 2) cast the four 512x512 fp32 weight matrices to bf16
// ---------------------------------------------------------------------------
__global__ __launch_bounds__(256) void cast_weights(const float* __restrict__ s0,
                                                    const float* __restrict__ s1,
                                                    const float* __restrict__ s2,
                                                    const float* __restrict__ s3,
                                                    short* __restrict__ d0,
                                                    short* __restrict__ d1,
                                                    short* __restrict__ d2,
                                                    short* __restrict__ d3) {
    int i = blockIdx.x * 256 + threadIdx.x;
    const float* s = (blockIdx.y == 0) ? s0 : (blockIdx.y == 1) ? s1 : (blockIdx.y == 2) ? s2 : s3;
    short* d = (blockIdx.y == 0) ? d0 : (blockIdx.y == 1) ? d1 : (blockIdx.y == 2) ? d2 : d3;
    d[i] = f2bs(s[i]);
}

// ---------------------------------------------------------------------------
// 3) FUSED q/k/v GEMM: 768 threads = 12 waves = 3 groups of 4.
//    Group g computes a 128x128 tile of matrix g (0=q,1=k,2=v); the XT (B)
//    tile is staged ONCE per K-step and shared by all 3 groups.
//    LDS: [As_q | As_k | As_v | Bs], each 128x32 bf16 = 8 KB -> 32 KB.
//    grid (32 n-tiles, 4 o-tiles, B). Per barrier-pair: 32 KB staged,
//    192 MFMA (3x the old per-barrier MFMA density).
// ---------------------------------------------------------------------------
__global__ __launch_bounds__(768) void gemm_qkv(const short* __restrict__ Wq,
                                                const short* __restrict__ Wk,
                                                const short* __restrict__ Wv,
                                                const short* __restrict__ XT,
                                                short* __restrict__ Yq,
                                                short* __restrict__ Yk,
                                                short* __restrict__ VT,
                                                float* __restrict__ Sq) {
    __shared__ __align__(16) short lds[4 * 128 * 32];   // 32 KB
    const int tid  = threadIdx.x;
    const int wave = tid >> 6;          // 0..11
    const int lane = tid & 63;
    const int g    = wave >> 2;         // matrix group 0=q,1=k,2=v
    const int wg   = wave & 3;          // wave within group
    const int n0 = blockIdx.x * 128;
    const int o0 = blockIdx.y * 128;
    const int b  = blockIdx.z;

    const short* Xg = XT + ((size_t)b * NPIX + n0) * CDIM;

    const int am = (wg >> 1) * 64;
    const int bn = (wg & 1) * 64;
    const int lrow = lane & 15;
    const int lk   = (lane >> 4) * 8;

    f32x4 acc[4][4] = {};

    for (int k0 = 0; k0 < CDIM; k0 += 32) {
        // stage 2048 16B-chunks: [As_q(512) | As_k(512) | As_v(512) | Bs(512)]
#pragma unroll
        for (int iss = 0; iss < 3; ++iss) {
            const int c = iss * 768 + tid;
            if (c < 2048) {                       // wave-uniform (boundary at 2048 = wave edge)
                const int m  = c >> 9;
                const int cc = c & 511;
                const int r  = cc >> 2;
                const int cq = (cc & 3) * 8;      // shorts
                const short* src =
                    (m == 0) ? Wq + (size_t)(o0 + r) * CDIM + k0 + cq :
                    (m == 1) ? Wk + (size_t)(o0 + r) * CDIM + k0 + cq :
                    (m == 2) ? Wv + (size_t)(o0 + r) * CDIM + k0 + cq :
                               Xg + (size_t)r * CDIM + k0 + cq;
                ld_lds16(src, lds + ((size_t)iss * 768 + wave * 64) * 8);
            }
        }
        __syncthreads();

        const short* As = lds + g * 4096;
        const short* Bs = lds + 3 * 4096;
        short8 afrag[4], bfrag[4];
#pragma unroll
        for (int i = 0; i < 4; ++i)
            afrag[i] = *(const short8*)&As[(am + i * 16 + lrow) * 32 + lk];
#pragma unroll
        for (int j = 0; j < 4; ++j)
            bfrag[j] = *(const short8*)&Bs[(bn + j * 16 + lrow) * 32 + lk];
#pragma unroll
        for (int i = 0; i < 4; ++i)
#pragma unroll
            for (int j = 0; j < 4; ++j)
                acc[i][j] = __builtin_amdgcn_mfma_f32_16x16x32_bf16(afrag[i], bfrag[j],
                                                                   acc[i][j], 0, 0, 0);
        __syncthreads();
    }

    const int crow = (lane >> 4) * 4;
    const int ccol = lane & 15;

    // fused squared-row-sums (L2-norm numerators) -> atomicAdd into Sq[g]
    {
        float sq[4][4];
#pragma unroll
        for (int i = 0; i < 4; ++i)
#pragma unroll
            for (int r = 0; r < 4; ++r) {
                float s = 0.f;
#pragma unroll
                for (int j = 0; j < 4; ++j) s += acc[i][j][r] * acc[i][j][r];
                s += __shfl_xor(s, 1); s += __shfl_xor(s, 2);
                s += __shfl_xor(s, 4); s += __shfl_xor(s, 8);
                sq[i][r] = s;
            }
        if (ccol == 0) {
            float* dstq = Sq + g * 4096 + b * CDIM + o0 + am;
#pragma unroll
            for (int i = 0; i < 4; ++i)
#pragma unroll
                for (int r = 0; r < 4; ++r)
                    atomicAdd(dstq + i * 16 + crow + r, sq[i][r]);
        }
    }

    if (g < 2) {
        // q,k: bf16 [b*512+c][n]
        short* Y = (g == 0) ? Yq : Yk;
#pragma unroll
        for (int i = 0; i < 4; ++i)
#pragma unroll
            for (int j = 0; j < 4; ++j)
#pragma unroll
                for (int r = 0; r < 4; ++r) {
                    const int om = o0 + am + i * 16 + crow + r;
                    const int on = n0 + bn + j * 16 + ccol;
                    Y[((size_t)b * CDIM + om) * NPIX + on] = f2bs(acc[i][j][r]);
                }
    } else {
        // v: transposed bf16 VT[b][n][c]
#pragma unroll
        for (int i = 0; i < 4; ++i)
#pragma unroll
            for (int j = 0; j < 4; ++j) {
                const int om = o0 + am + i * 16 + crow;       // +r contiguous
                const int on = n0 + bn + j * 16 + ccol;
                bf16x4 pk;
#pragma unroll
                for (int r = 0; r < 4; ++r) pk[r] = f2bs(acc[i][j][r]);
                *(bf16x4*)&VT[((size_t)b * NPIX + on) * CDIM + om] = pk;
            }
    }
}

// ---------------------------------------------------------------------------
// 4) proj GEMM (m97 structure), fp32 output [b][o][n]
// ---------------------------------------------------------------------------
__global__ __launch_bounds__(256) void gemm_f32(const short* __restrict__ W,
                                                const short* __restrict__ XT,
                                                float* __restrict__ Y) {
    __shared__ __align__(16) short As[128 * 32];
    __shared__ __align__(16) short Bs[128 * 32];
    const int tid  = threadIdx.x;
    const int wave = tid >> 6;
    const int lane = tid & 63;
    const int n0 = blockIdx.x * 128;
    const int o0 = blockIdx.y * 128;
    const int b  = blockIdx.z;
    const short* Wg = W + (size_t)o0 * CDIM;
    const short* Xg = XT + ((size_t)b * NPIX + n0) * CDIM;
    const int am = (wave >> 1) * 64;
    const int bn = (wave & 1) * 64;
    const int lrow = lane & 15;
    const int lk   = (lane >> 4) * 8;
    f32x4 acc[4][4] = {};
    for (int k0 = 0; k0 < CDIM; k0 += 32) {
#pragma unroll
        for (int i = 0; i < 2; ++i) {
            const int q = i * 256 + wave * 64 + lane;
            const int r = q >> 2;
            const int c = (q & 3) * 8;
            const int ldsoff = (i * 256 + wave * 64) * 8;
            ld_lds16(Wg + (size_t)r * CDIM + k0 + c, As + ldsoff);
            ld_lds16(Xg + (size_t)r * CDIM + k0 + c, Bs + ldsoff);
        }
        __syncthreads();
        short8 afrag[4], bfrag[4];
#pragma unroll
        for (int i = 0; i < 4; ++i)
            afrag[i] = *(const short8*)&As[(am + i * 16 + lrow) * 32 + lk];
#pragma unroll
        for (int j = 0; j < 4; ++j)
            bfrag[j] = *(const short8*)&Bs[(bn + j * 16 + lrow) * 32 + lk];
#pragma unroll
        for (int i = 0; i < 4; ++i)
#pragma unroll
            for (int j = 0; j < 4; ++j)
                acc[i][j] = __builtin_amdgcn_mfma_f32_16x16x32_bf16(afrag[i], bfrag[j],
                                                                   acc[i][j], 0, 0, 0);
        __syncthreads();
    }
    const int crow = (lane >> 4) * 4;
    const int ccol = lane & 15;
#pragma unroll
    for (int i = 0; i < 4; ++i)
#pragma unroll
        for (int j = 0; j < 4; ++j)
#pragma unroll
            for (int r = 0; r < 4; ++r) {
                const int om = o0 + am + i * 16 + crow + r;
                const int on = n0 + bn + j * 16 + ccol;
                Y[((size_t)b * CDIM + om) * NPIX + on] = acc[i][j][r];
            }
}

// ---------------------------------------------------------------------------
// 5) QK^T partials via MFMA
// ---------------------------------------------------------------------------
__global__ __launch_bounds__(256) void qk_mfma(const short* __restrict__ Q,
                                               const short* __restrict__ K,
                                               float* __restrict__ Spart) {
    __shared__ __align__(16) short Qs[64 * 32];
    __shared__ __align__(16) short Ks[64 * 32];
    const int tid = threadIdx.x;
    const int wave = tid >> 6;
    const int lane = tid & 63;
    const int kc = blockIdx.x;
    const int bh = blockIdx.y;
    const int kbase = kc * (NPIX / KCH);
    const short* qg = Q + (size_t)bh * HDIM * NPIX;
    const short* kg = K + (size_t)bh * HDIM * NPIX;
    const int lrow = lane & 15;
    const int lk = (lane >> 4) * 8;
    const int chunk = wave * 64 + lane;
    const int srow = chunk >> 2;
    const int scol = (chunk & 3) * 8;
    f32x4 acc[4] = {};
    for (int k0 = 0; k0 < NPIX / KCH; k0 += 32) {
        ld_lds16(qg + (size_t)srow * NPIX + kbase + k0 + scol, Qs + wave * 512);
        ld_lds16(kg + (size_t)srow * NPIX + kbase + k0 + scol, Ks + wave * 512);
        __syncthreads();
        short8 af = *(const short8*)&Qs[(wave * 16 + lrow) * 32 + lk];
#pragma unroll
        for (int j = 0; j < 4; ++j) {
            short8 bf = *(const short8*)&Ks[(j * 16 + lrow) * 32 + lk];
            acc[j] = __builtin_amdgcn_mfma_f32_16x16x32_bf16(af, bf, acc[j], 0, 0, 0);
        }
        __syncthreads();
    }
    float* sp = Spart + ((size_t)(kc * 64 + bh)) * 64 * 64;
    const int crow = (lane >> 4) * 4;
    const int ccol = lane & 15;
#pragma unroll
    for (int j = 0; j < 4; ++j)
#pragma unroll
        for (int r = 0; r < 4; ++r)
            sp[(wave * 16 + crow + r) * 64 + j * 16 + ccol] = acc[j][r];
}

// ---------------------------------------------------------------------------
// 6) reduce partials, apply norms+scale, softmax over e, fold rv; P bf16
// ---------------------------------------------------------------------------
__global__ __launch_bounds__(64) void softmax_p(const float* __restrict__ Spart,
                                                const float* __restrict__ Sq,
                                                short* __restrict__ P) {
    const int bh = blockIdx.x;
    const int d = threadIdx.x;
    __shared__ float rks[64], rvs[64];
    rks[d] = 1.0f / fmaxf(sqrtf(Sq[4096 + bh * 64 + d]), L2EPS);
    rvs[d] = 1.0f / fmaxf(sqrtf(Sq[8192 + bh * 64 + d]), L2EPS);
    __syncthreads();
    const float rqd = ATT_SCALE / fmaxf(sqrtf(Sq[bh * 64 + d]), L2EPS);
    float srow[64];
#pragma unroll
    for (int e = 0; e < 64; ++e) {
        float s = 0.f;
#pragma unroll
        for (int kc = 0; kc < KCH; ++kc)
            s += Spart[(((size_t)kc * 64 + bh) * 64 + d) * 64 + e];
        srow[e] = s * rqd * rks[e];
    }
    float m = -1e30f;
#pragma unroll
    for (int e = 0; e < 64; ++e) m = fmaxf(m, srow[e]);
    float sum = 0.f;
#pragma unroll
    for (int e = 0; e < 64; ++e) { float p = expf(srow[e] - m); srow[e] = p; sum += p; }
    const float inv = 1.f / sum;
    short* pp = P + (size_t)bh * 4096 + d * 64;
#pragma unroll
    for (int e = 0; e < 64; ++e) pp[e] = f2bs(srow[e] * inv * rvs[e]);
}

// ---------------------------------------------------------------------------
// 7) PV via MFMA: OT[b][n][h*64+d] = sum_e P[bh][d][e] * VT[b][n][h*64+e]
// ---------------------------------------------------------------------------
__global__ __launch_bounds__(256) void pv_mfma(const short* __restrict__ P,
                                               const short* __restrict__ VT,
                                               short* __restrict__ OT) {
    __shared__ __align__(16) short Ps[64 * 64];
    __shared__ __align__(16) short Vs[256 * 64];
    const int tid = threadIdx.x;
    const int wave = tid >> 6;
    const int lane = tid & 63;
    const int nc = blockIdx.x;
    const int bh = blockIdx.y;
    const int b = bh >> 3, h = bh & 7;
    const int n0 = nc * 256;
#pragma unroll
    for (int i = 0; i < 2; ++i) {
        const int cb = i * 256 + wave * 64;
        const int chunk = cb + lane;
        ld_lds16(P + (size_t)bh * 4096 + (chunk >> 3) * 64 + (chunk & 7) * 8,
                 Ps + cb * 8);
    }
#pragma unroll
    for (int i = 0; i < 8; ++i) {
        const int cb = i * 256 + wave * 64;
        const int chunk = cb + lane;
        ld_lds16(VT + ((size_t)b * NPIX + n0 + (chunk >> 3)) * CDIM + h * 64 + (chunk & 7) * 8,
                 Vs + cb * 8);
    }
    __syncthreads();
    const int lrow = lane & 15;
    const int lq = (lane >> 4) * 8;
    f32x4 acc[4][4] = {};
#pragma unroll
    for (int ks = 0; ks < 2; ++ks) {
        const int ko = ks * 32 + lq;
        short8 af[4], bf[4];
#pragma unroll
        for (int i = 0; i < 4; ++i)
            af[i] = *(const short8*)&Ps[(i * 16 + lrow) * 64 + ko];
#pragma unroll
        for (int j = 0; j < 4; ++j)
            bf[j] = *(const short8*)&Vs[(wave * 64 + j * 16 + lrow) * 64 + ko];
#pragma unroll
        for (int i = 0; i < 4; ++i)
#pragma unroll
            for (int j = 0; j < 4; ++j)
                acc[i][j] = __builtin_amdgcn_mfma_f32_16x16x32_bf16(af[i], bf[j],
                                                                   acc[i][j], 0, 0, 0);
    }
    const int crow = (lane >> 4) * 4;
    const int ccol = lane & 15;
#pragma unroll
    for (int i = 0; i < 4; ++i)
#pragma unroll
        for (int j = 0; j < 4; ++j) {
            const int n = n0 + wave * 64 + j * 16 + ccol;
            const int c = h * 64 + i * 16 + crow;
            bf16x4 pk;
#pragma unroll
            for (int r = 0; r < 4; ++r) pk[r] = f2bs(acc[i][j][r]);
            *(bf16x4*)&OT[((size_t)b * NPIX + n) * CDIM + c] = pk;
        }
}

// ---------------------------------------------------------------------------
extern "C" void kernel_launch(void* const* d_in, const int* in_sizes, int n_in,
                              void* d_out, int out_size, void* d_ws, size_t ws_size,
                              hipStream_t stream) {
    (void)in_sizes; (void)n_in; (void)out_size; (void)ws_size;
    const float* x      = (const float*)d_in[0];
    const float* dw_w   = (const float*)d_in[1];
    const float* q_w    = (const float*)d_in[2];
    const float* k_w    = (const float*)d_in[3];
    const float* v_w    = (const float*)d_in[4];
    const float* proj_w = (const float*)d_in[5];
    float* out = (float*)d_out;

    const size_t SZ = (size_t)BATCH * CDIM * NPIX;   // 16,777,216 elements
    float* ws = (float*)d_ws;
    short* OT  = (short*)ws;                               // SZ shorts
    float* Spart = ws + SZ / 2;                            // KCH*64*64*64 floats
    float* Sq    = Spart + (size_t)KCH * 64 * 64 * 64;     // 3*4096 fl (SqQ,SqK,SqV)
    short* Pb    = (short*)(Sq + 3 * 4096);                // 262,144 shorts
    short* wqb   = Pb + 262144;                            // 4 x 262,144 shorts
    short* wkb   = wqb + 262144;
    short* wvb   = wkb + 262144;
    short* wpb   = wvb + 262144;
    short* xdT = (short*)(ws + SZ);
    short* qb  = (short*)(ws + SZ + SZ / 2);
    short* kb  = (short*)(ws + 2 * SZ);
    short* vT  = (short*)(ws + 2 * SZ + SZ / 2);

    // 0) zero the squared-norm accumulators
    (void)hipMemsetAsync(Sq, 0, 3 * 4096 * sizeof(float), stream);

    // 1) fused dwconv3x3 + transpose + bf16 cast -> xdT
    dwconv_t<<<dim3(64 / STRIP, CDIM / 16, BATCH), 256, 0, stream>>>(x, dw_w, xdT);

    // 2) weights -> bf16
    cast_weights<<<dim3(262144 / 256, 4), 256, 0, stream>>>(q_w, k_w, v_w, proj_w,
                                                            wqb, wkb, wvb, wpb);

    // 3) FUSED q,k,v GEMM (shared XT staging, 12 waves, fused sq-sums)
    gemm_qkv<<<dim3(NPIX / 128, CDIM / 128, BATCH), 768, 0, stream>>>(
        wqb, wkb, wvb, xdT, qb, kb, vT, Sq);

    // 4) QK^T partials via MFMA
    qk_mfma<<<dim3(KCH, BATCH * NHEAD), 256, 0, stream>>>(qb, kb, Spart);

    // 5) softmax (+ norms + scale + rv folded), P bf16
    softmax_p<<<BATCH * NHEAD, 64, 0, stream>>>(Spart, Sq, Pb);

    // 6) PV via MFMA -> OT bf16 [b][n][c] (proj input layout)
    pv_mfma<<<dim3(16, BATCH * NHEAD), 256, 0, stream>>>(Pb, vT, OT);

    // 7) projection conv1x1 -> fp32 out
    gemm_f32<<<dim3(NPIX / 128, CDIM / 128, BATCH), 256, 0, stream>>>(wpb, OT, out);
}